// Round 8
// baseline (181.451 us; speedup 1.0000x reference)
//
#include <hip/hip_runtime.h>

// Problem constants (fixed by the reference):
//   TOTAL_NODES = 262144, NUM_GRAPHS = 1024, MAX_NODES = 512, D = 256
#define NUM_GRAPHS 1024
#define MAX_NODES  512
#define DIM        256
#define D4         (DIM / 4)          // 64 float4 per row (1 KB) = one wave-load

typedef float f4 __attribute__((ext_vector_type(4)));

// lower_bound over the sorted batch_idx (int64 or int32 storage).
__device__ __forceinline__ int lower_bound_idx(const int* __restrict__ b, int n,
                                               bool is64, int key) {
    int lo = 0, hi = n;
    while (lo < hi) {
        int mid = (lo + hi) >> 1;
        int v = is64 ? b[2 * mid] : b[mid];
        if (v < key) lo = mid + 1; else hi = mid;
    }
    return lo;
}

// Per-block metadata: threads 0/1 binary-search starts[g]/starts[g+1].
// bidx is 1-2 MB -> L2-resident; ~18 dependent loads, parallel across blocks.
__device__ __forceinline__ void block_meta(const int* __restrict__ bidx32, int n,
                                           int g, int* sc) {
    if (threadIdx.x < 2) {
        // int64 detect: little-endian int64 values < 2^31 => int32 view at
        // index n-1 is a hi-word == 0; int32 => max graph id (nonzero here).
        const bool is64 = (bidx32[n - 1] == 0);
        sc[threadIdx.x] = lower_bound_idx(bidx32, n, is64, g + threadIdx.x);
    }
    __syncthreads();
}

// ---------------------------------------------------------------------------
// PHASE-HOMOGENEOUS DECOMPOSITION. All prior single-kernel variants blend a
// 1:1 R:W copy stream with a pure-W fill stream and plateau at 4.7 TB/s;
// the proven ceilings (copy 6.29 TB/s, fill 6.7 TB/s) are both homogeneous.
// Split: copy kernel (occupied rows, 268R+268W) + fill kernel (padding rows
// + mask, ~271W). Same total traffic, each phase runs pure.
// ---------------------------------------------------------------------------

// Kernel A: copy rows [0, c) of graph g from emb rows [s, s+c).
// Wave w handles a contiguous quarter of the occupied rows.
__global__ void __launch_bounds__(256)
copy_kernel(const f4* __restrict__ emb, const int* __restrict__ bidx32, int n,
            f4* __restrict__ out) {
    __shared__ int sc[2];
    const int g = blockIdx.x;
    block_meta(bidx32, n, g, sc);
    const int s = sc[0];
    const int c = sc[1] - sc[0];

    const int lane = threadIdx.x & 63;
    const int w    = threadIdx.x >> 6;        // 0..3
    const int q    = (c + 3) >> 2;
    const int r0   = min(w * q, c);
    const int r1   = min(r0 + q, c);

    const f4* wemb = emb + (size_t)(s + r0) * D4 + lane;
    f4*       wout = out + ((size_t)g * MAX_NODES + r0) * D4 + lane;
    const int cnt  = r1 - r0;
#pragma unroll 8
    for (int it = 0; it < cnt; ++it)
        wout[it * D4] = wemb[it * D4];
}

// Kernel B: zero-fill rows [c, 512) of graph g, plus the 512-entry mask.
__global__ void __launch_bounds__(256)
fill_kernel(const int* __restrict__ bidx32, int n,
            f4* __restrict__ out, float* __restrict__ mask) {
    __shared__ int sc[2];
    const int g = blockIdx.x;
    block_meta(bidx32, n, g, sc);
    const int c   = sc[1] - sc[0];
    const int pad = MAX_NODES - c;

    const int lane = threadIdx.x & 63;
    const int w    = threadIdx.x >> 6;        // 0..3
    const int q    = (pad + 3) >> 2;
    const int r0   = min(w * q, pad);
    const int r1   = min(r0 + q, pad);

    f4* wout = out + ((size_t)g * MAX_NODES + c + r0) * D4 + lane;
    const int cnt = r1 - r0;
    const f4 z = (f4)(0.f);
#pragma unroll 8
    for (int it = 0; it < cnt; ++it)
        wout[it * D4] = z;

    // enc_mask: 512 f32 for this graph, 2 per thread.
    float* mg = mask + (size_t)g * MAX_NODES;
    mg[threadIdx.x]       = ((int)threadIdx.x < c)       ? 1.0f : 0.0f;
    mg[256 + threadIdx.x] = (256 + (int)threadIdx.x < c) ? 1.0f : 0.0f;
}

extern "C" void kernel_launch(void* const* d_in, const int* in_sizes, int n_in,
                              void* d_out, int out_size, void* d_ws, size_t ws_size,
                              hipStream_t stream) {
    const float* node_emb = (const float*)d_in[0];
    const int*   bidx32   = (const int*)d_in[1];   // int32 view; kernels detect int64
    const int    n        = in_sizes[1];           // 262144

    float* mask = (float*)d_out + (size_t)NUM_GRAPHS * MAX_NODES * DIM;

    copy_kernel<<<NUM_GRAPHS, 256, 0, stream>>>(
        (const f4*)node_emb, bidx32, n, (f4*)d_out);
    fill_kernel<<<NUM_GRAPHS, 256, 0, stream>>>(
        bidx32, n, (f4*)d_out, mask);
}